// Round 13
// baseline (83.281 us; speedup 1.0000x reference)
//
#include <hip/hip_runtime.h>
#include <hip/hip_bf16.h>
#include <math.h>

constexpr int NQ   = 22500;      // 150*150
constexpr int NQP  = 22528;      // 176*128
constexpr int GH   = 150, GW = 150;

using f32x4 = __attribute__((ext_vector_type(4))) float;
using s16x8 = __attribute__((ext_vector_type(8))) short;

__device__ inline ushort f2bf(float f) {
    __hip_bfloat16 h = __float2bfloat16(f);
    return *reinterpret_cast<ushort*>(&h);
}
__device__ inline float bflo(uint u) { return __builtin_bit_cast(float, u << 16); }
__device__ inline float bfhi(uint u) { return __builtin_bit_cast(float, u & 0xffff0000u); }
__device__ inline float bf2f(uint u) { return __builtin_bit_cast(float, (u & 0xffffu) << 16); }

__device__ inline void gload_lds16(const void* g, void* l) {
    __builtin_amdgcn_global_load_lds(
        (const __attribute__((address_space(1))) void*)g,
        (__attribute__((address_space(3))) void*)l, 16, 0, 0);
}

constexpr int CAST_BLOCKS = NQP * 64 / 256;                    // 5632
constexpr int PREP_ITEMS  = 448 * 512 + 65536 + 448;           // 295360
constexpr int PREP_BLOCKS = (PREP_ITEMS + 255) / 256;          // 1154

// ---------------------------------------------------------------------------
// Merged front prep: blocks [0, CAST_BLOCKS) build qcat; the rest transpose
// weights (rides free under the BW-bound cast).
// qcat[NQP][512] bf16 = [query | query+query_pos] (pad rows zeroed)
// Bcat[448][512] = [W_v(zero-pad k>=256) | W_off | W_attn]^T (K-major)
// WoutT[256][256], bcat[448] = [b_v | b_off | b_attn]
// ---------------------------------------------------------------------------
__global__ __launch_bounds__(256) void prep_kernel(
    const float* __restrict__ query, const float* __restrict__ qpos,
    const float* __restrict__ Wv, const float* __restrict__ Woff,
    const float* __restrict__ Wattn, const float* __restrict__ Wout,
    const float* __restrict__ bv, const float* __restrict__ boff,
    const float* __restrict__ battn,
    ushort* __restrict__ qcat, ushort* __restrict__ Bcat,
    ushort* __restrict__ WoutT, float* __restrict__ bcat)
{
    if (blockIdx.x < CAST_BLOCKS) {
        const int t = blockIdx.x * 256 + threadIdx.x;   // 8 bf16 each
        const int q = t >> 6, c8 = (t & 63) * 8;
        s16x8 o = {};
        if (q < NQ) {
            if (c8 < 256) {
                const float4* p = (const float4*)(query + (size_t)q * 256 + c8);
                const float4 a = p[0], b = p[1];
                o[0]=f2bf(a.x); o[1]=f2bf(a.y); o[2]=f2bf(a.z); o[3]=f2bf(a.w);
                o[4]=f2bf(b.x); o[5]=f2bf(b.y); o[6]=f2bf(b.z); o[7]=f2bf(b.w);
            } else {
                const float4* p1 = (const float4*)(query + (size_t)q * 256 + c8 - 256);
                const float4* p2 = (const float4*)(qpos  + (size_t)q * 256 + c8 - 256);
                const float4 a = p1[0], b = p1[1], c = p2[0], d = p2[1];
                o[0]=f2bf(a.x+c.x); o[1]=f2bf(a.y+c.y); o[2]=f2bf(a.z+c.z); o[3]=f2bf(a.w+c.w);
                o[4]=f2bf(b.x+d.x); o[5]=f2bf(b.y+d.y); o[6]=f2bf(b.z+d.z); o[7]=f2bf(b.w+d.w);
            }
        }
        *(s16x8*)&qcat[(size_t)q * 512 + c8] = o;
        return;
    }
    int t = (blockIdx.x - CAST_BLOCKS) * 256 + threadIdx.x;
    if (t < 448 * 512) {
        const int col = t >> 9, k = t & 511;
        float v = 0.f;
        if (col < 256)      { if (k < 256) v = Wv[k * 256 + col]; }
        else if (col < 384) v = Woff[k * 128 + (col - 256)];
        else                v = Wattn[k * 64 + (col - 384)];
        Bcat[t] = f2bf(v);
        return;
    }
    t -= 448 * 512;
    if (t < 65536) { const int n = t >> 8, k = t & 255; WoutT[t] = f2bf(Wout[k * 256 + n]); return; }
    t -= 65536;
    if (t < 448) bcat[t] = t < 256 ? bv[t] : (t < 384 ? boff[t - 256] : battn[t - 384]);
}

// ---------------------------------------------------------------------------
// Measured-best GEMM (r9 = 78.7us): 128x64 tile, BK=32, 2-phase dbuf LDS
// 2x12 KB, 4 waves (2x2). STAGE(next) first, ds_read + 8 MFMA, ONE barrier.
// ~6 blocks/CU — cross-block TLP is what hides the barrier drain here.
// MODE 0 (front): A=qcat(512), B=Bcat[448][512]; by<4: value (K=256),
//   by>=4: off/attn (K=512); bf16 out split value/offattn.
// MODE 1 (out):   A=msda(256), B=WoutT[256][256], K=256; f32 out
//   = acc + bias + identity(query).
// ---------------------------------------------------------------------------
template <int MODE>
__global__ __launch_bounds__(256) void gemm_kernel(
    const ushort* __restrict__ A, const ushort* __restrict__ Bt,
    const float* __restrict__ bias, const float* __restrict__ ident,
    ushort* __restrict__ o_value, ushort* __restrict__ o_offattn,
    float* __restrict__ o_f32)
{
    constexpr int LDA = (MODE == 0) ? 512 : 256;
    constexpr int LDB = (MODE == 0) ? 512 : 256;
    constexpr int BK = 32;
    __shared__ ushort As[2][128 * BK];   // 2 x 8 KB
    __shared__ ushort Bs[2][64 * BK];    // 2 x 4 KB

    const int tid  = threadIdx.x;
    const int lane = tid & 63;
    const int w    = tid >> 6;
    const int wm   = w >> 1, wn = w & 1;
    const int l15  = lane & 15, l4 = lane >> 4;
    const int brow = blockIdx.x * 128;
    const int bcol = blockIdx.y * 64;
    const int ksteps = (MODE == 0) ? ((blockIdx.y < 4) ? 8 : 16) : 8;

    f32x4 acc[4][2] = {};

    auto STAGE = [&](int b, int ks) {
        const int k0 = ks * BK;
#pragma unroll
        for (int c = 0; c < 2; ++c) {
            const int idx = c * 256 + tid;
            gload_lds16(A + (size_t)(brow + (idx >> 2)) * LDA + k0 + (idx & 3) * 8,
                        (char*)As[b] + (c * 256 + w * 64) * 16);
        }
        gload_lds16(Bt + (size_t)(bcol + (tid >> 2)) * LDB + k0 + (tid & 3) * 8,
                    (char*)Bs[b] + (w * 64) * 16);
    };

    STAGE(0, 0);
    __syncthreads();

    int buf = 0;
    for (int ks = 0; ks < ksteps; ++ks) {
        if (ks + 1 < ksteps) STAGE(buf ^ 1, ks + 1);

        s16x8 a[4], b[2];
#pragma unroll
        for (int mi = 0; mi < 4; ++mi)
            a[mi] = *(const s16x8*)&As[buf][(wm * 64 + mi * 16 + l15) * BK + l4 * 8];
#pragma unroll
        for (int ni = 0; ni < 2; ++ni)
            b[ni] = *(const s16x8*)&Bs[buf][(wn * 32 + ni * 16 + l15) * BK + l4 * 8];
#pragma unroll
        for (int mi = 0; mi < 4; ++mi)
#pragma unroll
            for (int ni = 0; ni < 2; ++ni)
                acc[mi][ni] = __builtin_amdgcn_mfma_f32_16x16x32_bf16(
                    a[mi], b[ni], acc[mi][ni], 0, 0, 0);

        if (ks + 1 < ksteps) __syncthreads();
        buf ^= 1;
    }

    // Epilogue (C/D: col=lane&15, row=(lane>>4)*4+r)
#pragma unroll
    for (int mi = 0; mi < 4; ++mi) {
#pragma unroll
        for (int r = 0; r < 4; ++r) {
            const int gr = brow + wm * 64 + mi * 16 + l4 * 4 + r;
#pragma unroll
            for (int ni = 0; ni < 2; ++ni) {
                const int gc = bcol + wn * 32 + ni * 16 + l15;
                if (MODE == 0) {
                    const float v = acc[mi][ni][r] + bias[gc];
                    if (gc < 256) o_value[(size_t)gr * 256 + gc] = f2bf(v);
                    else          o_offattn[(size_t)gr * 192 + gc - 256] = f2bf(v);
                } else {
                    if (gr < NQ)
                        o_f32[(size_t)gr * 256 + gc] =
                            acc[mi][ni][r] + bias[gc] + ident[(size_t)gr * 256 + gc];
                }
            }
        }
    }
}

// ---------------------------------------------------------------------------
// Fused prep + gather, v3: block = 8 queries. Prep: 2 passes x 256 threads
// = 512 point-records (1 per (q,h,j,p)); softmax via 4-lane shfl_xor; tail
// queries (q>=NQ) write zeroed records. Gather: each HALF-WAVE (32 lanes)
// owns one query; lane owns 8 channels via uint4 (16B) loads — halves
// load/address instruction count vs uint2.
// ---------------------------------------------------------------------------
__global__ __launch_bounds__(256) void msda_fused_kernel(
    const ushort* __restrict__ value_bf,   // NQ x 256
    const ushort* __restrict__ offattn,    // NQ x 192
    const float* __restrict__ refpts,      // (2, NQ, 1, 2)
    ushort* __restrict__ msda_bf)          // NQ x 256
{
    __shared__ uint4 Plds[8 * 64];

    constexpr int NB = (NQ + 7) / 8;   // 2813
    constexpr int NX = 8;
    constexpr int qd = NB / NX, rr = NB % NX;   // 351, 5
    const int bid = blockIdx.x;
    const int xcd = bid % NX, loc = bid / NX;
    const int swz = (xcd < rr ? xcd * (qd + 1) : rr * (qd + 1) + (xcd - rr) * qd) + loc;
    const int qbase = swz * 8;
    const int tid = threadIdx.x;

    // ---- prep: 2 passes, one point-record per thread per pass ----
#pragma unroll
    for (int pass = 0; pass < 2; ++pass) {
        const int rec = pass * 256 + tid;     // ql*64 + r
        const int ql  = rec >> 6;
        const int r   = rec & 63;             // = h*8 + j*4 + p
        const int q   = qbase + ql;
        uint4 P = {0u, 0u, 0u, 0u};
        if (q < NQ) {
            const int jj = (r >> 2) & 1;
            const float lg = bf2f(offattn[(size_t)q * 192 + 128 + r]);
            float mx = fmaxf(lg, __shfl_xor(lg, 1));
            mx = fmaxf(mx, __shfl_xor(mx, 2));
            const float e = expf(lg - mx);
            float s = e + __shfl_xor(e, 1);
            s = s + __shfl_xor(s, 2);
            const float aw = e * (0.5f / s);

            const uint opk = *(const uint*)(offattn + (size_t)q * 192 + r * 2);
            const float2 rp = *(const float2*)(refpts + ((size_t)jj * NQ + q) * 2);
            const float x = rp.x * 150.f - 0.5f + bflo(opk);
            const float y = rp.y * 150.f - 0.5f + bfhi(opk);
            const float x0f = floorf(x), y0f = floorf(y);
            const float wx = x - x0f, wy = y - y0f;
            const int x0 = (int)x0f, y0 = (int)y0f;
            const float vx0 = (x0 >= 0 && x0 < GW) ? 1.f : 0.f;
            const float vx1 = (x0 >= -1 && x0 < GW - 1) ? 1.f : 0.f;
            const float vy0 = (y0 >= 0 && y0 < GH) ? 1.f : 0.f;
            const float vy1 = (y0 >= -1 && y0 < GH - 1) ? 1.f : 0.f;
            const int ix0 = min(max(x0, 0), GW - 1), ix1 = min(max(x0 + 1, 0), GW - 1);
            const int iy0 = min(max(y0, 0), GH - 1), iy1 = min(max(y0 + 1, 0), GH - 1);
            const float w00 = (1.f - wx) * (1.f - wy) * aw * vx0 * vy0;
            const float w01 = wx * (1.f - wy) * aw * vx1 * vy0;
            const float w10 = (1.f - wx) * wy * aw * vx0 * vy1;
            const float w11 = wx * wy * aw * vx1 * vy1;
            P.x = (uint)(iy0 * GW + ix0) | ((uint)(iy0 * GW + ix1) << 16);
            P.y = (uint)(iy1 * GW + ix0) | ((uint)(iy1 * GW + ix1) << 16);
            P.z = (uint)f2bf(w00) | ((uint)f2bf(w01) << 16);
            P.w = (uint)f2bf(w10) | ((uint)f2bf(w11) << 16);
        }
        Plds[rec] = P;
    }
    __syncthreads();

    // ---- gather: half-wave per query, lane owns 8 channels (uint4) ----
    const int wv = tid >> 6;
    const int l  = tid & 63;
    const int ql = wv * 2 + (l >> 5);      // 0..7
    const int q  = qbase + ql;
    const int cl = l & 31;
    const int c0 = cl * 8;                 // channel base
    const int h  = cl >> 2;                // head
    const uint cb = (uint)c0 * 2;          // byte offset in value row
    const uint4* pp = &Plds[ql * 64 + h * 8];
    const char* vbase = (const char*)value_bf;

    float a0 = 0.f, a1 = 0.f, a2 = 0.f, a3 = 0.f;
    float a4 = 0.f, a5 = 0.f, a6 = 0.f, a7 = 0.f;
#pragma unroll
    for (int pt = 0; pt < 8; ++pt) {
        const uint4 P = pp[pt];
#pragma unroll
        for (int cr = 0; cr < 4; ++cr) {
            const uint idxw = (cr < 2) ? P.x : P.y;
            const uint wpk  = (cr < 2) ? P.z : P.w;
            const uint pix  = (cr & 1) ? (idxw >> 16) : (idxw & 0xffffu);
            const float wgt = (cr & 1) ? bfhi(wpk) : bflo(wpk);
            const uint4 v = *(const uint4*)(vbase + ((size_t)(pix << 9) + cb));
            a0 = fmaf(wgt, bflo(v.x), a0);
            a1 = fmaf(wgt, bfhi(v.x), a1);
            a2 = fmaf(wgt, bflo(v.y), a2);
            a3 = fmaf(wgt, bfhi(v.y), a3);
            a4 = fmaf(wgt, bflo(v.z), a4);
            a5 = fmaf(wgt, bfhi(v.z), a5);
            a6 = fmaf(wgt, bflo(v.w), a6);
            a7 = fmaf(wgt, bfhi(v.w), a7);
        }
    }
    if (q < NQ) {
        s16x8 o;
        o[0] = (short)f2bf(a0); o[1] = (short)f2bf(a1);
        o[2] = (short)f2bf(a2); o[3] = (short)f2bf(a3);
        o[4] = (short)f2bf(a4); o[5] = (short)f2bf(a5);
        o[6] = (short)f2bf(a6); o[7] = (short)f2bf(a7);
        *(s16x8*)&msda_bf[(size_t)q * 256 + c0] = o;
    }
}

// ---------------------------------------------------------------------------
extern "C" void kernel_launch(void* const* d_in, const int* in_sizes, int n_in,
                              void* d_out, int out_size, void* d_ws, size_t ws_size,
                              hipStream_t stream)
{
    const float* query     = (const float*)d_in[0];
    const float* query_pos = (const float*)d_in[1];
    const float* refpts    = (const float*)d_in[2];
    const float* W_off     = (const float*)d_in[3];
    const float* b_off     = (const float*)d_in[4];
    const float* W_attn    = (const float*)d_in[5];
    const float* b_attn    = (const float*)d_in[6];
    const float* W_v       = (const float*)d_in[7];
    const float* b_v       = (const float*)d_in[8];
    const float* W_out     = (const float*)d_in[9];
    const float* b_out     = (const float*)d_in[10];
    float* out             = (float*)d_out;

    char* base = (char*)d_ws;
    size_t o = 0;
    ushort* qcat     = (ushort*)(base + o); o += (size_t)NQP * 512 * 2;
    ushort* value_bf = (ushort*)(base + o); o += (size_t)NQP * 256 * 2;
    ushort* offattn  = (ushort*)(base + o); o += (size_t)NQP * 192 * 2;
    ushort* msda_bf  = (ushort*)(base + o); o += (size_t)NQP * 256 * 2;
    ushort* Bcat     = (ushort*)(base + o); o += 448 * 512 * 2;
    ushort* WoutT    = (ushort*)(base + o); o += 256 * 256 * 2;
    float*  bcat     = (float*)(base + o);  o += 448 * 4;

    prep_kernel<<<CAST_BLOCKS + PREP_BLOCKS, 256, 0, stream>>>(
        query, query_pos, W_v, W_off, W_attn, W_out, b_v, b_off, b_attn,
        qcat, Bcat, WoutT, bcat);

    // front: value (y<4, K=256) + off/attn (y>=4, K=512), one launch
    gemm_kernel<0><<<dim3(NQP / 128, 7), 256, 0, stream>>>(
        qcat, Bcat, bcat, nullptr, value_bf, offattn, nullptr);

    msda_fused_kernel<<<(NQ + 7) / 8, 256, 0, stream>>>(value_bf, offattn, refpts, msda_bf);

    gemm_kernel<1><<<dim3(NQP / 128, 4), 256, 0, stream>>>(
        msda_bf, WoutT, b_out, query, nullptr, nullptr, out);
}

// Round 14
// 76.643 us; speedup vs baseline: 1.0866x; 1.0866x over previous
//
#include <hip/hip_runtime.h>
#include <hip/hip_bf16.h>
#include <math.h>

constexpr int NQ   = 22500;      // 150*150
constexpr int NQP  = 22528;      // 176*128
constexpr int GH   = 150, GW = 150;

using f32x4 = __attribute__((ext_vector_type(4))) float;
using s16x8 = __attribute__((ext_vector_type(8))) short;

__device__ inline ushort f2bf(float f) {
    __hip_bfloat16 h = __float2bfloat16(f);
    return *reinterpret_cast<ushort*>(&h);
}
__device__ inline float bflo(uint u) { return __builtin_bit_cast(float, u << 16); }
__device__ inline float bfhi(uint u) { return __builtin_bit_cast(float, u & 0xffff0000u); }
__device__ inline float bf2f(uint u) { return __builtin_bit_cast(float, (u & 0xffffu) << 16); }

__device__ inline void gload_lds16(const void* g, void* l) {
    __builtin_amdgcn_global_load_lds(
        (const __attribute__((address_space(1))) void*)g,
        (__attribute__((address_space(3))) void*)l, 16, 0, 0);
}

constexpr int CAST_BLOCKS = NQP * 32 / 256;                    // 2816
constexpr int PREP_ITEMS  = 448 * 512 + 65536 + 448;           // 295360
constexpr int PREP_BLOCKS = (PREP_ITEMS + 255) / 256;          // 1154

// ---------------------------------------------------------------------------
// Merged front prep. Cast blocks: 32 threads/row, each handles cols c8 and
// c8+256 from ONE query load (halves query HBM reads vs two-pass layout).
// qcat[NQP][512] bf16 = [query | query+query_pos] (pad rows zeroed)
// Bcat[448][512] = [W_v(zero-pad k>=256) | W_off | W_attn]^T (K-major)
// WoutT[256][256], bcat[448] = [b_v | b_off | b_attn]
// ---------------------------------------------------------------------------
__global__ __launch_bounds__(256) void prep_kernel(
    const float* __restrict__ query, const float* __restrict__ qpos,
    const float* __restrict__ Wv, const float* __restrict__ Woff,
    const float* __restrict__ Wattn, const float* __restrict__ Wout,
    const float* __restrict__ bv, const float* __restrict__ boff,
    const float* __restrict__ battn,
    ushort* __restrict__ qcat, ushort* __restrict__ Bcat,
    ushort* __restrict__ WoutT, float* __restrict__ bcat)
{
    if (blockIdx.x < CAST_BLOCKS) {
        const int t = blockIdx.x * 256 + threadIdx.x;   // 8 cols, both halves
        const int q = t >> 5, c8 = (t & 31) * 8;
        s16x8 lo = {}, hi = {};
        if (q < NQ) {
            const float4* pq = (const float4*)(query + (size_t)q * 256 + c8);
            const float4* pp = (const float4*)(qpos  + (size_t)q * 256 + c8);
            const float4 a = pq[0], b = pq[1], c = pp[0], d = pp[1];
            lo[0]=f2bf(a.x); lo[1]=f2bf(a.y); lo[2]=f2bf(a.z); lo[3]=f2bf(a.w);
            lo[4]=f2bf(b.x); lo[5]=f2bf(b.y); lo[6]=f2bf(b.z); lo[7]=f2bf(b.w);
            hi[0]=f2bf(a.x+c.x); hi[1]=f2bf(a.y+c.y); hi[2]=f2bf(a.z+c.z); hi[3]=f2bf(a.w+c.w);
            hi[4]=f2bf(b.x+d.x); hi[5]=f2bf(b.y+d.y); hi[6]=f2bf(b.z+d.z); hi[7]=f2bf(b.w+d.w);
        }
        *(s16x8*)&qcat[(size_t)q * 512 + c8]       = lo;
        *(s16x8*)&qcat[(size_t)q * 512 + 256 + c8] = hi;
        return;
    }
    int t = (blockIdx.x - CAST_BLOCKS) * 256 + threadIdx.x;
    if (t < 448 * 512) {
        const int col = t >> 9, k = t & 511;
        float v = 0.f;
        if (col < 256)      { if (k < 256) v = Wv[k * 256 + col]; }
        else if (col < 384) v = Woff[k * 128 + (col - 256)];
        else                v = Wattn[k * 64 + (col - 384)];
        Bcat[t] = f2bf(v);
        return;
    }
    t -= 448 * 512;
    if (t < 65536) { const int n = t >> 8, k = t & 255; WoutT[t] = f2bf(Wout[k * 256 + n]); return; }
    t -= 65536;
    if (t < 448) bcat[t] = t < 256 ? bv[t] : (t < 384 ? boff[t - 256] : battn[t - 384]);
}

// ---------------------------------------------------------------------------
// Measured-best GEMM (r9 = 78.7us): 128x64 tile, BK=32, 2-phase dbuf LDS
// 2x12 KB, 4 waves (2x2). STAGE(next) first, ds_read + 8 MFMA, ONE barrier.
// ~6 blocks/CU — cross-block TLP is what hides the barrier drain here.
// MODE 0 (front): A=qcat(512), B=Bcat[448][512]; by<4: value (K=256),
//   by>=4: off/attn (K=512); bf16 out split value/offattn.
// MODE 1 (out):   A=msda(256), B=WoutT[256][256], K=256; f32 out
//   = acc + bias + identity(query).
// ---------------------------------------------------------------------------
template <int MODE>
__global__ __launch_bounds__(256) void gemm_kernel(
    const ushort* __restrict__ A, const ushort* __restrict__ Bt,
    const float* __restrict__ bias, const float* __restrict__ ident,
    ushort* __restrict__ o_value, ushort* __restrict__ o_offattn,
    float* __restrict__ o_f32)
{
    constexpr int LDA = (MODE == 0) ? 512 : 256;
    constexpr int LDB = (MODE == 0) ? 512 : 256;
    constexpr int BK = 32;
    __shared__ ushort As[2][128 * BK];   // 2 x 8 KB
    __shared__ ushort Bs[2][64 * BK];    // 2 x 4 KB

    const int tid  = threadIdx.x;
    const int lane = tid & 63;
    const int w    = tid >> 6;
    const int wm   = w >> 1, wn = w & 1;
    const int l15  = lane & 15, l4 = lane >> 4;
    const int brow = blockIdx.x * 128;
    const int bcol = blockIdx.y * 64;
    const int ksteps = (MODE == 0) ? ((blockIdx.y < 4) ? 8 : 16) : 8;

    f32x4 acc[4][2] = {};

    auto STAGE = [&](int b, int ks) {
        const int k0 = ks * BK;
#pragma unroll
        for (int c = 0; c < 2; ++c) {
            const int idx = c * 256 + tid;
            gload_lds16(A + (size_t)(brow + (idx >> 2)) * LDA + k0 + (idx & 3) * 8,
                        (char*)As[b] + (c * 256 + w * 64) * 16);
        }
        gload_lds16(Bt + (size_t)(bcol + (tid >> 2)) * LDB + k0 + (tid & 3) * 8,
                    (char*)Bs[b] + (w * 64) * 16);
    };

    STAGE(0, 0);
    __syncthreads();

    int buf = 0;
    for (int ks = 0; ks < ksteps; ++ks) {
        if (ks + 1 < ksteps) STAGE(buf ^ 1, ks + 1);

        s16x8 a[4], b[2];
#pragma unroll
        for (int mi = 0; mi < 4; ++mi)
            a[mi] = *(const s16x8*)&As[buf][(wm * 64 + mi * 16 + l15) * BK + l4 * 8];
#pragma unroll
        for (int ni = 0; ni < 2; ++ni)
            b[ni] = *(const s16x8*)&Bs[buf][(wn * 32 + ni * 16 + l15) * BK + l4 * 8];
#pragma unroll
        for (int mi = 0; mi < 4; ++mi)
#pragma unroll
            for (int ni = 0; ni < 2; ++ni)
                acc[mi][ni] = __builtin_amdgcn_mfma_f32_16x16x32_bf16(
                    a[mi], b[ni], acc[mi][ni], 0, 0, 0);

        if (ks + 1 < ksteps) __syncthreads();
        buf ^= 1;
    }

    // Epilogue (C/D: col=lane&15, row=(lane>>4)*4+r)
#pragma unroll
    for (int mi = 0; mi < 4; ++mi) {
#pragma unroll
        for (int r = 0; r < 4; ++r) {
            const int gr = brow + wm * 64 + mi * 16 + l4 * 4 + r;
#pragma unroll
            for (int ni = 0; ni < 2; ++ni) {
                const int gc = bcol + wn * 32 + ni * 16 + l15;
                if (MODE == 0) {
                    const float v = acc[mi][ni][r] + bias[gc];
                    if (gc < 256) o_value[(size_t)gr * 256 + gc] = f2bf(v);
                    else          o_offattn[(size_t)gr * 192 + gc - 256] = f2bf(v);
                } else {
                    if (gr < NQ)
                        o_f32[(size_t)gr * 256 + gc] =
                            acc[mi][ni][r] + bias[gc] + ident[(size_t)gr * 256 + gc];
                }
            }
        }
    }
}

// ---------------------------------------------------------------------------
// Fused prep + gather (r9 structure + XOR-swizzled Plds).
// Block = 4 waves = 4 queries (XCD-swizzled). Record (h,pt) stored at slot
// h*8+(pt^h): read banks 4*(pt^h) distinct across h (was 8-way same-bank),
// writes remain conflict-free (per-8-lane permutation of a linear layout).
// ---------------------------------------------------------------------------
__global__ __launch_bounds__(256) void msda_fused_kernel(
    const ushort* __restrict__ value_bf,   // NQ x 256
    const ushort* __restrict__ offattn,    // NQ x 192
    const float* __restrict__ refpts,      // (2, NQ, 1, 2)
    ushort* __restrict__ msda_bf)          // NQ x 256
{
    __shared__ uint4 Plds[4 * 64];

    constexpr int NB = NQ / 4;         // 5625
    constexpr int NX = 8;
    constexpr int qd = NB / NX, rr = NB % NX;
    const int bid = blockIdx.x;
    const int xcd = bid % NX, loc = bid / NX;
    const int swz = (xcd < rr ? xcd * (qd + 1) : rr * (qd + 1) + (xcd - rr) * qd) + loc;

    const int wv   = threadIdx.x >> 6;
    const int lane = threadIdx.x & 63;
    const int q    = swz * 4 + wv;

    // ---- prep: one point per lane ----
    {
        const int jj = (lane >> 2) & 1;
        const float lg = bf2f(offattn[(size_t)q * 192 + 128 + lane]);
        float mx = fmaxf(lg, __shfl_xor(lg, 1));
        mx = fmaxf(mx, __shfl_xor(mx, 2));
        const float e = expf(lg - mx);
        float s = e + __shfl_xor(e, 1);
        s = s + __shfl_xor(s, 2);
        const float aw = e * (0.5f / s);

        const uint opk = *(const uint*)(offattn + (size_t)q * 192 + lane * 2);
        const float2 rp = *(const float2*)(refpts + ((size_t)jj * NQ + q) * 2);
        const float x = rp.x * 150.f - 0.5f + bflo(opk);
        const float y = rp.y * 150.f - 0.5f + bfhi(opk);
        const float x0f = floorf(x), y0f = floorf(y);
        const float wx = x - x0f, wy = y - y0f;
        const int x0 = (int)x0f, y0 = (int)y0f;
        const float vx0 = (x0 >= 0 && x0 < GW) ? 1.f : 0.f;
        const float vx1 = (x0 >= -1 && x0 < GW - 1) ? 1.f : 0.f;
        const float vy0 = (y0 >= 0 && y0 < GH) ? 1.f : 0.f;
        const float vy1 = (y0 >= -1 && y0 < GH - 1) ? 1.f : 0.f;
        const int ix0 = min(max(x0, 0), GW - 1), ix1 = min(max(x0 + 1, 0), GW - 1);
        const int iy0 = min(max(y0, 0), GH - 1), iy1 = min(max(y0 + 1, 0), GH - 1);
        const float w00 = (1.f - wx) * (1.f - wy) * aw * vx0 * vy0;
        const float w01 = wx * (1.f - wy) * aw * vx1 * vy0;
        const float w10 = (1.f - wx) * wy * aw * vx0 * vy1;
        const float w11 = wx * wy * aw * vx1 * vy1;
        uint4 P;
        P.x = (uint)(iy0 * GW + ix0) | ((uint)(iy0 * GW + ix1) << 16);
        P.y = (uint)(iy1 * GW + ix0) | ((uint)(iy1 * GW + ix1) << 16);
        P.z = (uint)f2bf(w00) | ((uint)f2bf(w01) << 16);
        P.w = (uint)f2bf(w10) | ((uint)f2bf(w11) << 16);
        const int hh = lane >> 3, pp0 = lane & 7;
        Plds[wv * 64 + hh * 8 + (pp0 ^ hh)] = P;
    }
    __syncthreads();

    // ---- gather: lane = h*8+cl owns 4 channels ----
    const int h  = lane >> 3;
    const int cl = lane & 7;
    const int c0 = h * 32 + cl * 4;
    const uint cb = (uint)c0 * 2;
    const uint4* pp = &Plds[wv * 64 + h * 8];
    const char* vbase = (const char*)value_bf;

    float a0 = 0.f, a1 = 0.f, a2 = 0.f, a3 = 0.f;
#pragma unroll
    for (int pt = 0; pt < 8; ++pt) {
        const uint4 P = pp[pt ^ h];
#pragma unroll
        for (int cr = 0; cr < 4; ++cr) {
            const uint idxw = (cr < 2) ? P.x : P.y;
            const uint wpk  = (cr < 2) ? P.z : P.w;
            const uint pix  = (cr & 1) ? (idxw >> 16) : (idxw & 0xffffu);
            const float wgt = (cr & 1) ? bfhi(wpk) : bflo(wpk);
            const uint2 v = *(const uint2*)(vbase + ((size_t)(pix << 9) + cb));
            a0 = fmaf(wgt, bflo(v.x), a0);
            a1 = fmaf(wgt, bfhi(v.x), a1);
            a2 = fmaf(wgt, bflo(v.y), a2);
            a3 = fmaf(wgt, bfhi(v.y), a3);
        }
    }
    ushort4 o;
    o.x = f2bf(a0); o.y = f2bf(a1); o.z = f2bf(a2); o.w = f2bf(a3);
    *(ushort4*)&msda_bf[(size_t)q * 256 + c0] = o;
}

// ---------------------------------------------------------------------------
extern "C" void kernel_launch(void* const* d_in, const int* in_sizes, int n_in,
                              void* d_out, int out_size, void* d_ws, size_t ws_size,
                              hipStream_t stream)
{
    const float* query     = (const float*)d_in[0];
    const float* query_pos = (const float*)d_in[1];
    const float* refpts    = (const float*)d_in[2];
    const float* W_off     = (const float*)d_in[3];
    const float* b_off     = (const float*)d_in[4];
    const float* W_attn    = (const float*)d_in[5];
    const float* b_attn    = (const float*)d_in[6];
    const float* W_v       = (const float*)d_in[7];
    const float* b_v       = (const float*)d_in[8];
    const float* W_out     = (const float*)d_in[9];
    const float* b_out     = (const float*)d_in[10];
    float* out             = (float*)d_out;

    char* base = (char*)d_ws;
    size_t o = 0;
    ushort* qcat     = (ushort*)(base + o); o += (size_t)NQP * 512 * 2;
    ushort* value_bf = (ushort*)(base + o); o += (size_t)NQP * 256 * 2;
    ushort* offattn  = (ushort*)(base + o); o += (size_t)NQP * 192 * 2;
    ushort* msda_bf  = (ushort*)(base + o); o += (size_t)NQP * 256 * 2;
    ushort* Bcat     = (ushort*)(base + o); o += 448 * 512 * 2;
    ushort* WoutT    = (ushort*)(base + o); o += 256 * 256 * 2;
    float*  bcat     = (float*)(base + o);  o += 448 * 4;

    prep_kernel<<<CAST_BLOCKS + PREP_BLOCKS, 256, 0, stream>>>(
        query, query_pos, W_v, W_off, W_attn, W_out, b_v, b_off, b_attn,
        qcat, Bcat, WoutT, bcat);

    // front: value (y<4, K=256) + off/attn (y>=4, K=512), one launch
    gemm_kernel<0><<<dim3(NQP / 128, 7), 256, 0, stream>>>(
        qcat, Bcat, bcat, nullptr, value_bf, offattn, nullptr);

    msda_fused_kernel<<<NQ / 4, 256, 0, stream>>>(value_bf, offattn, refpts, msda_bf);

    gemm_kernel<1><<<dim3(NQP / 128, 4), 256, 0, stream>>>(
        msda_bf, WoutT, b_out, query, nullptr, nullptr, out);
}